// Round 2
// baseline (881.545 us; speedup 1.0000x reference)
//
#include <hip/hip_runtime.h>
#include <hip/hip_cooperative_groups.h>

#define CAP 48

typedef short  s8v  __attribute__((ext_vector_type(8)));
typedef float  f4v  __attribute__((ext_vector_type(4)));

__device__ __forceinline__ unsigned short f2bf(float f) {
    unsigned u = __float_as_uint(f);
    u += 0x7FFFu + ((u >> 16) & 1u);      // RNE
    return (unsigned short)(u >> 16);
}
__device__ __forceinline__ float bflo(unsigned v) { return __uint_as_float(v << 16); }
__device__ __forceinline__ float bfhi(unsigned v) { return __uint_as_float(v & 0xffff0000u); }

#define ACC8(A_, v) do { (A_)[0]+=bflo((v).x); (A_)[1]+=bfhi((v).x); (A_)[2]+=bflo((v).y); (A_)[3]+=bfhi((v).y); \
                         (A_)[4]+=bflo((v).z); (A_)[5]+=bfhi((v).z); (A_)[6]+=bflo((v).w); (A_)[7]+=bfhi((v).w); } while(0)

struct KArgs {
    const int* src; const int* dst;
    const float* x;
    const float* W[6];
    const float *g1, *be1, *rm1, *rv1, *bl1;
    const float *g2, *be2, *rm2, *rv2, *bl2;
    const float* bl3;
    int* cnt; int* bucket;
    unsigned short* xb; unsigned short* hb; unsigned short* hb2; unsigned short* t3b;
    unsigned short* Wp[6];
    float* P;
    float* outf;
    int N, E, nbBucket, nbCvt, nbL;
};

// ---- stage A unit: bucket CSR | x->bf16 convert | weight pack | BN fold ----
__device__ void prep_unit(int b, const KArgs& A) {
    const int tid = threadIdx.x;
    if (b < A.nbBucket) {
        int e = b * 256 + tid;
        if (e < A.E) {
            int d = A.dst[e];
            int slot = atomicAdd(A.cnt + d, 1);
            if (slot < CAP) A.bucket[(size_t)d * CAP + slot] = A.src[e];
        }
        return;
    }
    b -= A.nbBucket;
    if (b < A.nbCvt) {
        int i = b * 256 + tid;
        int n4 = A.N * 32;                       // N*128/4
        if (i < n4) {
            float4 v = ((const float4*)A.x)[i];
            ushort4 o;
            o.x = f2bf(v.x); o.y = f2bf(v.y); o.z = f2bf(v.z); o.w = f2bf(v.w);
            ((ushort4*)A.xb)[i] = o;
        }
        return;
    }
    b -= A.nbCvt;
    const int px = b & 63;
    const int py = b >> 6;
    if (py == 6) {
        if (px == 0 && tid < 128) {
            int i = tid;
            float s1 = A.g1[i] * rsqrtf(A.rv1[i] + 1e-5f);
            A.P[i]       = s1;
            A.P[128 + i] = (A.bl1[i] - A.rm1[i]) * s1 + A.be1[i];
            float s2 = A.g2[i] * rsqrtf(A.rv2[i] + 1e-5f);
            A.P[256 + i] = s2;
            A.P[384 + i] = (A.bl2[i] - A.rm2[i]) * s2 + A.be2[i];
            // zero row N of each feature buffer (gather padding target)
            A.xb [(size_t)A.N * 128 + i] = 0;
            A.hb [(size_t)A.N * 128 + i] = 0;
            A.hb2[(size_t)A.N * 128 + i] = 0;
            if (i < 64) A.t3b[(size_t)A.N * 64 + i] = 0;
        }
        return;
    }
    const float* W = A.W[py];
    unsigned short* Pk = A.Wp[py];
    const int JD = (py >= 4) ? 64 : 128;
    int o = px * 256 + tid;
    if (o >= 128 * JD) return;
    int j    = o & 7;
    int lane = (o >> 3) & 63;
    int t    = o >> 9;
    int nt   = t % (JD / 16);
    int kt   = t / (JD / 16);
    int k = kt * 32 + (lane >> 4) * 8 + j;
    int nn = nt * 16 + (lane & 15);
    Pk[o] = f2bf(W[(size_t)k * JD + nn]);
}

// ---- fused SAGE layer unit: gather-mean -> LDS, dual MFMA, BN+ReLU --------
// 32 nodes/unit, 4 waves. Gather: quarter-wave per node (16 lanes x uint4),
// 2 serial slots/wave, burst-8 rounds via zero-row clamping (round-0 shape).
template<bool T3>
__device__ void layer_unit(int u, const KArgs& A,
                           const unsigned short* __restrict__ feat,
                           const unsigned short* __restrict__ Bl,
                           const unsigned short* __restrict__ Br,
                           const float* __restrict__ scale,
                           const float* __restrict__ shift,
                           unsigned short* __restrict__ out,
                           const unsigned short* __restrict__ W3p,
                           unsigned short* __restrict__ t3,
                           unsigned short* sA, unsigned short* sH) {
    const int n = A.N;
    const int* __restrict__ cnt    = A.cnt;
    const int* __restrict__ bucket = A.bucket;
    const int tid  = threadIdx.x;
    const int wave = tid >> 6;
    const int lane = tid & 63;
    const int nb0  = u * 32;

    // ---- phase 1: gather-mean ----------------------------------------------
    {
        const int q4   = lane >> 4;
        const int li   = lane & 15;
        const int base = q4 << 4;
        const uint4* inp = (const uint4*)feat;     // 256B row = 16 x uint4
        int rows[2], cs[2], idxs[2];
        #pragma unroll
        for (int t = 0; t < 2; t++) {
            rows[t] = wave * 8 + t * 4 + q4;
            int node = nb0 + rows[t];
            bool ok = node < n;
            int c = ok ? cnt[node] : 0; if (c > CAP) c = CAP;
            cs[t] = c;
            idxs[t] = (ok && li < c) ? bucket[(size_t)node * CAP + li] : n;  // n = zero row
        }
        #pragma unroll
        for (int t = 0; t < 2; t++) {
            const int c = cs[t];
            float a[8] = {0.f, 0.f, 0.f, 0.f, 0.f, 0.f, 0.f, 0.f};
            if (c > 0) {
                #pragma unroll
                for (int uu = 0; uu < 8; uu++) {
                    int idx = __shfl(idxs[t], base + uu);       // >=c lanes hold n (zero row)
                    uint4 v = inp[(size_t)idx * 16 + li];
                    ACC8(a, v);
                }
            }
            if (c > 8) {
                #pragma unroll
                for (int uu = 8; uu < 16; uu++) {
                    int idx = __shfl(idxs[t], base + uu);
                    uint4 v = inp[(size_t)idx * 16 + li];
                    ACC8(a, v);
                }
            }
            const int node = nb0 + rows[t];
            for (int s = 16; s < c; s++) {                      // deg>16 (rare)
                int idx = bucket[(size_t)node * CAP + s];
                uint4 v = inp[(size_t)idx * 16 + li];
                ACC8(a, v);
            }
            if (node < n) {
                float iv = 1.0f / fmaxf((float)c, 1.0f);
                uint4 o;
                o.x = (unsigned)f2bf(a[0] * iv) | ((unsigned)f2bf(a[1] * iv) << 16);
                o.y = (unsigned)f2bf(a[2] * iv) | ((unsigned)f2bf(a[3] * iv) << 16);
                o.z = (unsigned)f2bf(a[4] * iv) | ((unsigned)f2bf(a[5] * iv) << 16);
                o.w = (unsigned)f2bf(a[6] * iv) | ((unsigned)f2bf(a[7] * iv) << 16);
                *(uint4*)(sA + rows[t] * 136 + li * 8) = o;
            }
        }
    }
    __syncthreads();

    // ---- phase 2: dual MFMA, wave = 32 rows x 32 cols (nt0 = wave*2) --------
    const int m = lane & 15;
    const int q = lane >> 4;
    const int nt0 = wave * 2;
    const int rg0 = min(nb0 + m,      n - 1);
    const int rg1 = min(nb0 + 16 + m, n - 1);

    f4v acc[2][2];
    #pragma unroll
    for (int mt = 0; mt < 2; mt++)
        #pragma unroll
        for (int c = 0; c < 2; c++) {
            acc[mt][c][0] = 0.f; acc[mt][c][1] = 0.f; acc[mt][c][2] = 0.f; acc[mt][c][3] = 0.f;
        }

    #pragma unroll
    for (int kt = 0; kt < 4; kt++) {
        const int ko = kt * 32 + q * 8;
        s8v a0 = *(const s8v*)(sA + m * 136 + ko);                // agg side (LDS)
        s8v a1 = *(const s8v*)(sA + (16 + m) * 136 + ko);
        s8v a0d = *(const s8v*)(feat + (size_t)rg0 * 128 + ko);   // root side (global)
        s8v a1d = *(const s8v*)(feat + (size_t)rg1 * 128 + ko);
        #pragma unroll
        for (int c = 0; c < 2; c++) {
            s8v b  = *(const s8v*)(Bl + ((size_t)(kt * 8 + nt0 + c) * 64 + lane) * 8);
            acc[0][c] = __builtin_amdgcn_mfma_f32_16x16x32_bf16(a0, b, acc[0][c], 0, 0, 0);
            acc[1][c] = __builtin_amdgcn_mfma_f32_16x16x32_bf16(a1, b, acc[1][c], 0, 0, 0);
            s8v b2 = *(const s8v*)(Br + ((size_t)(kt * 8 + nt0 + c) * 64 + lane) * 8);
            acc[0][c] = __builtin_amdgcn_mfma_f32_16x16x32_bf16(a0d, b2, acc[0][c], 0, 0, 0);
            acc[1][c] = __builtin_amdgcn_mfma_f32_16x16x32_bf16(a1d, b2, acc[1][c], 0, 0, 0);
        }
    }

    // ---- epilogue: BN+ReLU, write bf16 (and stash tile for t3) -------------
    float scv[2], shv[2];
    #pragma unroll
    for (int c = 0; c < 2; c++) {
        int col = (nt0 + c) * 16 + m;
        scv[c] = scale[col]; shv[c] = shift[col];
    }
    #pragma unroll
    for (int mt = 0; mt < 2; mt++) {
        #pragma unroll
        for (int reg = 0; reg < 4; reg++) {
            int rloc = mt * 16 + q * 4 + reg;
            int row  = nb0 + rloc;
            if (row < n) {
                #pragma unroll
                for (int c = 0; c < 2; c++) {
                    int col = (nt0 + c) * 16 + m;
                    float v = fmaxf(acc[mt][c][reg] * scv[c] + shv[c], 0.f);
                    unsigned short uq = f2bf(v);
                    out[(size_t)row * 128 + col] = uq;
                    if constexpr (T3) sH[rloc * 136 + col] = uq;
                }
            }
        }
    }

    // ---- phase 3 (layer 2 only): t3 = hb2_tile @ Wl3, wave = 16 cols -------
    if constexpr (T3) {
        __syncthreads();
        f4v a3c[2];
        #pragma unroll
        for (int mt = 0; mt < 2; mt++) { a3c[mt][0] = 0.f; a3c[mt][1] = 0.f; a3c[mt][2] = 0.f; a3c[mt][3] = 0.f; }
        #pragma unroll
        for (int kt = 0; kt < 4; kt++) {
            const int ko = kt * 32 + q * 8;
            s8v a0 = *(const s8v*)(sH + m * 136 + ko);
            s8v a1 = *(const s8v*)(sH + (16 + m) * 136 + ko);
            s8v b  = *(const s8v*)(W3p + ((size_t)(kt * 4 + wave) * 64 + lane) * 8);
            a3c[0] = __builtin_amdgcn_mfma_f32_16x16x32_bf16(a0, b, a3c[0], 0, 0, 0);
            a3c[1] = __builtin_amdgcn_mfma_f32_16x16x32_bf16(a1, b, a3c[1], 0, 0, 0);
        }
        #pragma unroll
        for (int mt = 0; mt < 2; mt++) {
            #pragma unroll
            for (int reg = 0; reg < 4; reg++) {
                int row = nb0 + mt * 16 + q * 4 + reg;
                if (row < n) t3[(size_t)row * 64 + wave * 16 + m] = f2bf(a3c[mt][reg]);
            }
        }
    }
}

// ---- layer-3 unit: gather-mean(t3) + hb2@Wr3 + bias ------------------------
__device__ void final_unit(int u, const KArgs& A, float* sG) {
    const int n = A.N;
    const unsigned short* __restrict__ hb2 = A.hb2;
    const int* __restrict__ cnt    = A.cnt;
    const int* __restrict__ bucket = A.bucket;
    const int tid  = threadIdx.x;
    const int wave = tid >> 6;
    const int lane = tid & 63;
    const int nb0  = u * 32;

    // ---- phase 1: gather-mean ----------------------------------------------
    {
        const int e8   = lane >> 3;
        const int li   = lane & 7;
        const int base = e8 << 3;
        const uint4* inp = (const uint4*)A.t3b;    // 128B row = 8 x uint4
        const int row  = wave * 8 + e8;
        const int node = nb0 + row;
        const bool ok  = node < n;
        int c = ok ? cnt[node] : 0; if (c > CAP) c = CAP;
        int idx1 = (ok && li < c)     ? bucket[(size_t)node * CAP + li]     : n;
        int idx2 = (ok && li + 8 < c) ? bucket[(size_t)node * CAP + li + 8] : n;
        float a[8] = {0.f, 0.f, 0.f, 0.f, 0.f, 0.f, 0.f, 0.f};
        if (c > 0) {
            #pragma unroll
            for (int uu = 0; uu < 8; uu++) {
                int idx = __shfl(idx1, base + uu);
                uint4 v = inp[(size_t)idx * 8 + li];
                ACC8(a, v);
            }
        }
        if (c > 8) {
            #pragma unroll
            for (int uu = 0; uu < 8; uu++) {
                int idx = __shfl(idx2, base + uu);
                uint4 v = inp[(size_t)idx * 8 + li];
                ACC8(a, v);
            }
        }
        for (int s = 16; s < c; s++) {             // deg>16 (rare)
            int idx = bucket[(size_t)node * CAP + s];
            uint4 v = inp[(size_t)idx * 8 + li];
            ACC8(a, v);
        }
        if (ok) {
            float iv = 1.0f / fmaxf((float)c, 1.0f);
            float4 o1; o1.x = a[0] * iv; o1.y = a[1] * iv; o1.z = a[2] * iv; o1.w = a[3] * iv;
            float4 o2; o2.x = a[4] * iv; o2.y = a[5] * iv; o2.z = a[6] * iv; o2.w = a[7] * iv;
            *(float4*)(sG + row * 68 + li * 8)     = o1;
            *(float4*)(sG + row * 68 + li * 8 + 4) = o2;
        }
    }
    __syncthreads();

    // ---- phase 2: out = hb2 @ Wr3 + agg + bias ------------------------------
    const int m = lane & 15;
    const int q = lane >> 4;
    const int rg0 = min(nb0 + m,      n - 1);
    const int rg1 = min(nb0 + 16 + m, n - 1);

    f4v acc[2];
    #pragma unroll
    for (int mt = 0; mt < 2; mt++) { acc[mt][0] = 0.f; acc[mt][1] = 0.f; acc[mt][2] = 0.f; acc[mt][3] = 0.f; }

    #pragma unroll
    for (int kt = 0; kt < 4; kt++) {
        const int ko = kt * 32 + q * 8;
        s8v a0 = *(const s8v*)(hb2 + (size_t)rg0 * 128 + ko);
        s8v a1 = *(const s8v*)(hb2 + (size_t)rg1 * 128 + ko);
        s8v b  = *(const s8v*)(A.Wp[5] + ((size_t)(kt * 4 + wave) * 64 + lane) * 8);
        acc[0] = __builtin_amdgcn_mfma_f32_16x16x32_bf16(a0, b, acc[0], 0, 0, 0);
        acc[1] = __builtin_amdgcn_mfma_f32_16x16x32_bf16(a1, b, acc[1], 0, 0, 0);
    }

    const int col = wave * 16 + m;
    const float bv = A.bl3[col];
    #pragma unroll
    for (int mt = 0; mt < 2; mt++) {
        #pragma unroll
        for (int reg = 0; reg < 4; reg++) {
            int rloc = mt * 16 + q * 4 + reg;
            int row  = nb0 + rloc;
            if (row < n) A.outf[(size_t)row * 64 + col] = acc[mt][reg] + sG[rloc * 68 + col] + bv;
        }
    }
}

// ---- the mega-kernel: prep | sync | L1 | sync | L2 | sync | L3 -------------
__global__ __launch_bounds__(256, 8) void k_all(KArgs A) {
    __shared__ __align__(16) unsigned short sA[32 * 136];
    __shared__ __align__(16) unsigned short sH[32 * 136];
    cooperative_groups::grid_group gg = cooperative_groups::this_grid();

    const int UA = A.nbBucket + A.nbCvt + 448;
    for (int b = blockIdx.x; b < UA; b += gridDim.x)
        prep_unit(b, A);
    gg.sync();

    for (int u = blockIdx.x; u < A.nbL; u += gridDim.x) {
        layer_unit<false>(u, A, A.xb, A.Wp[0], A.Wp[1], A.P, A.P + 128,
                          A.hb, nullptr, nullptr, sA, sH);
        __syncthreads();
    }
    gg.sync();

    for (int u = blockIdx.x; u < A.nbL; u += gridDim.x) {
        layer_unit<true>(u, A, A.hb, A.Wp[2], A.Wp[3], A.P + 256, A.P + 384,
                         A.hb2, A.Wp[4], A.t3b, sA, sH);
        __syncthreads();
    }
    gg.sync();

    for (int u = blockIdx.x; u < A.nbL; u += gridDim.x) {
        final_unit(u, A, (float*)sA);
        __syncthreads();
    }
}

extern "C" void kernel_launch(void* const* d_in, const int* in_sizes, int n_in,
                              void* d_out, int out_size, void* d_ws, size_t ws_size,
                              hipStream_t stream) {
    const float* x   = (const float*)d_in[0];
    const int*   ei  = (const int*)d_in[1];

    const int N = in_sizes[0] / 128;
    const int E = in_sizes[1] / 2;

    // workspace layout (feature buffers have N+1 rows; row N is the zero row)
    char* w = (char*)d_ws;
    auto au = [](size_t v) { return (v + 1023) & ~(size_t)1023; };
    size_t off = 0;
    int*            cnt    = (int*)(w + off);            off += au((size_t)N * 4);
    int*            bucket = (int*)(w + off);            off += au((size_t)N * CAP * 4);
    unsigned short* xb     = (unsigned short*)(w + off); off += au((size_t)(N + 1) * 128 * 2);
    unsigned short* hb     = (unsigned short*)(w + off); off += au((size_t)(N + 1) * 128 * 2);
    unsigned short* hb2    = (unsigned short*)(w + off); off += au((size_t)(N + 1) * 128 * 2);
    unsigned short* t3b    = (unsigned short*)(w + off); off += au((size_t)(N + 1) * 64 * 2);
    unsigned short* Wp[6];
    Wp[0] = (unsigned short*)(w + off); off += au(128 * 128 * 2);  // Wl1
    Wp[1] = (unsigned short*)(w + off); off += au(128 * 128 * 2);  // Wr1
    Wp[2] = (unsigned short*)(w + off); off += au(128 * 128 * 2);  // Wl2
    Wp[3] = (unsigned short*)(w + off); off += au(128 * 128 * 2);  // Wr2
    Wp[4] = (unsigned short*)(w + off); off += au(128 * 64 * 2);   // Wl3
    Wp[5] = (unsigned short*)(w + off); off += au(128 * 64 * 2);   // Wr3
    float* P = (float*)(w + off); off += 2048;
    (void)ws_size; (void)n_in;

    KArgs A;
    A.src = ei; A.dst = ei + E;
    A.x   = x;
    A.W[0] = (const float*)d_in[2];   // Wl1
    A.bl1  = (const float*)d_in[3];
    A.W[1] = (const float*)d_in[4];   // Wr1
    A.g1   = (const float*)d_in[5];
    A.be1  = (const float*)d_in[6];
    A.rm1  = (const float*)d_in[7];
    A.rv1  = (const float*)d_in[8];
    A.W[2] = (const float*)d_in[9];   // Wl2
    A.bl2  = (const float*)d_in[10];
    A.W[3] = (const float*)d_in[11];  // Wr2
    A.g2   = (const float*)d_in[12];
    A.be2  = (const float*)d_in[13];
    A.rm2  = (const float*)d_in[14];
    A.rv2  = (const float*)d_in[15];
    A.W[4] = (const float*)d_in[16];  // Wl3
    A.bl3  = (const float*)d_in[17];
    A.W[5] = (const float*)d_in[18];  // Wr3
    A.cnt = cnt; A.bucket = bucket;
    A.xb = xb; A.hb = hb; A.hb2 = hb2; A.t3b = t3b;
    for (int i = 0; i < 6; i++) A.Wp[i] = Wp[i];
    A.P = P;
    A.outf = (float*)d_out;
    A.N = N; A.E = E;
    A.nbBucket = (E + 255) / 256;
    A.nbCvt    = (N * 32 + 255) / 256;
    A.nbL      = (N + 31) / 32;

    // grid sized for guaranteed co-residency (cooperative launch)
    static int gridBlocks = 0;
    if (gridBlocks == 0) {
        int dev = 0;
        hipGetDevice(&dev);
        hipDeviceProp_t prop;
        hipGetDeviceProperties(&prop, dev);
        int nb = 0;
        hipOccupancyMaxActiveBlocksPerMultiprocessor(&nb, k_all, 256, 0);
        if (nb < 1) nb = 1;
        gridBlocks = nb * prop.multiProcessorCount;
        if (gridBlocks > 4096) gridBlocks = 4096;
        if (gridBlocks < 1) gridBlocks = 1;
    }

    hipMemsetAsync(cnt, 0, (size_t)N * 4, stream);
    void* params[] = { (void*)&A };
    hipLaunchCooperativeKernel((const void*)k_all, dim3(gridBlocks), dim3(256),
                               params, 0, stream);
}

// Round 4
// 305.268 us; speedup vs baseline: 2.8878x; 2.8878x over previous
//
#include <hip/hip_runtime.h>

#define CAP 48

typedef short  s8v  __attribute__((ext_vector_type(8)));
typedef float  f4v  __attribute__((ext_vector_type(4)));

__device__ __forceinline__ unsigned short f2bf(float f) {
    unsigned u = __float_as_uint(f);
    u += 0x7FFFu + ((u >> 16) & 1u);      // RNE
    return (unsigned short)(u >> 16);
}
__device__ __forceinline__ float bflo(unsigned v) { return __uint_as_float(v << 16); }
__device__ __forceinline__ float bfhi(unsigned v) { return __uint_as_float(v & 0xffff0000u); }

#define ACC8(A_, v) do { (A_)[0]+=bflo((v).x); (A_)[1]+=bfhi((v).x); (A_)[2]+=bflo((v).y); (A_)[3]+=bfhi((v).y); \
                         (A_)[4]+=bflo((v).z); (A_)[5]+=bfhi((v).z); (A_)[6]+=bflo((v).w); (A_)[7]+=bfhi((v).w); } while(0)

// ---- merged prep: bucket CSR + x->bf16 convert + weight pack + BN fold -----
__global__ __launch_bounds__(256) void k_prep(const int* __restrict__ src, const int* __restrict__ dst, int E,
                                              int* __restrict__ cnt, int* __restrict__ bucket,
                                              const float* __restrict__ x, unsigned short* __restrict__ xb, int n4,
                                              const float* W0, const float* W1, const float* W2,
                                              const float* W3, const float* W4, const float* W5,
                                              unsigned short* P0, unsigned short* P1, unsigned short* P2,
                                              unsigned short* P3, unsigned short* P4, unsigned short* P5,
                                              const float* g1, const float* be1, const float* rm1, const float* rv1, const float* bl1,
                                              const float* g2, const float* be2, const float* rm2, const float* rv2, const float* bl2,
                                              float* P,
                                              unsigned short* hb, unsigned short* hb2, unsigned short* t3b, int N,
                                              int nbBucket, int nbCvt) {
    int b = blockIdx.x;
    const int tid = threadIdx.x;
    if (b < nbBucket) {
        int e = b * 256 + tid;
        if (e < E) {
            int d = dst[e];
            int slot = atomicAdd(&cnt[d], 1);
            if (slot < CAP) bucket[(size_t)d * CAP + slot] = src[e];
        }
        return;
    }
    b -= nbBucket;
    if (b < nbCvt) {
        int i = b * 256 + tid;
        if (i < n4) {
            float4 v = ((const float4*)x)[i];
            ushort4 o;
            o.x = f2bf(v.x); o.y = f2bf(v.y); o.z = f2bf(v.z); o.w = f2bf(v.w);
            ((ushort4*)xb)[i] = o;
        }
        return;
    }
    b -= nbCvt;
    const int px = b & 63;
    const int py = b >> 6;
    if (py == 6) {
        if (px == 0 && tid < 128) {
            int i = tid;
            float s1 = g1[i] * rsqrtf(rv1[i] + 1e-5f);
            P[i]       = s1;
            P[128 + i] = (bl1[i] - rm1[i]) * s1 + be1[i];
            float s2 = g2[i] * rsqrtf(rv2[i] + 1e-5f);
            P[256 + i] = s2;
            P[384 + i] = (bl2[i] - rm2[i]) * s2 + be2[i];
            // zero row N of each feature buffer (gather padding target)
            xb [(size_t)N * 128 + i] = 0;
            hb [(size_t)N * 128 + i] = 0;
            hb2[(size_t)N * 128 + i] = 0;
            if (i < 64) t3b[(size_t)N * 64 + i] = 0;
        }
        return;
    }
    const float* W; unsigned short* Pk; int JD;
    switch (py) {
        case 0: W = W0; Pk = P0; JD = 128; break;
        case 1: W = W1; Pk = P1; JD = 128; break;
        case 2: W = W2; Pk = P2; JD = 128; break;
        case 3: W = W3; Pk = P3; JD = 128; break;
        case 4: W = W4; Pk = P4; JD = 64;  break;
        default:W = W5; Pk = P5; JD = 64;  break;
    }
    int o = px * 256 + tid;
    if (o >= 128 * JD) return;
    int j    = o & 7;
    int lane = (o >> 3) & 63;
    int t    = o >> 9;
    int nt   = t % (JD / 16);
    int kt   = t / (JD / 16);
    int k = kt * 32 + (lane >> 4) * 8 + j;
    int nn = nt * 16 + (lane & 15);
    Pk[o] = f2bf(W[(size_t)k * JD + nn]);
}

// ---- fused SAGE layer: gather-mean -> LDS, dual MFMA, BN+ReLU epilogue -----
// Persistent blocks: grid-stride over 32-node units (2 units/block).
template<bool T3>
__global__ __launch_bounds__(256) void k_fused(const unsigned short* __restrict__ feat,
                                               const int* __restrict__ cnt, const int* __restrict__ bucket,
                                               const unsigned short* __restrict__ Bl, const unsigned short* __restrict__ Br,
                                               const float* __restrict__ scale, const float* __restrict__ shift,
                                               unsigned short* __restrict__ out,
                                               const unsigned short* __restrict__ W3p, unsigned short* __restrict__ t3,
                                               int n, int units) {
    __shared__ unsigned short sA[32 * 136];
    __shared__ unsigned short sH[T3 ? 32 * 136 : 8];
    const int tid  = threadIdx.x;
    const int wave = tid >> 6;
    const int lane = tid & 63;

    for (int u = blockIdx.x; u < units; u += gridDim.x) {
        const int nb0 = u * 32;

        // ---- phase 1: gather-mean ------------------------------------------
        {
            const int q4   = lane >> 4;
            const int li   = lane & 15;
            const int base = q4 << 4;
            const uint4* inp = (const uint4*)feat;     // 256B row = 16 x uint4
            int rows[2], cs[2], idxs[2];
            #pragma unroll
            for (int t = 0; t < 2; t++) {
                rows[t] = wave * 8 + t * 4 + q4;
                int node = nb0 + rows[t];
                bool ok = node < n;
                int c = ok ? cnt[node] : 0; if (c > CAP) c = CAP;
                cs[t] = c;
                idxs[t] = (ok && li < c) ? bucket[(size_t)node * CAP + li] : n;  // n = zero row
            }
            #pragma unroll
            for (int t = 0; t < 2; t++) {
                const int c = cs[t];
                float a[8] = {0.f, 0.f, 0.f, 0.f, 0.f, 0.f, 0.f, 0.f};
                if (c > 0) {
                    #pragma unroll
                    for (int uu = 0; uu < 8; uu++) {
                        int idx = __shfl(idxs[t], base + uu);   // >=c lanes hold n (zero row)
                        uint4 v = inp[(size_t)idx * 16 + li];
                        ACC8(a, v);
                    }
                }
                if (c > 8) {
                    #pragma unroll
                    for (int uu = 8; uu < 16; uu++) {
                        int idx = __shfl(idxs[t], base + uu);
                        uint4 v = inp[(size_t)idx * 16 + li];
                        ACC8(a, v);
                    }
                }
                const int node = nb0 + rows[t];
                for (int s = 16; s < c; s++) {                  // deg>16 (rare)
                    int idx = bucket[(size_t)node * CAP + s];
                    uint4 v = inp[(size_t)idx * 16 + li];
                    ACC8(a, v);
                }
                if (node < n) {
                    float iv = 1.0f / fmaxf((float)c, 1.0f);
                    uint4 o;
                    o.x = (unsigned)f2bf(a[0] * iv) | ((unsigned)f2bf(a[1] * iv) << 16);
                    o.y = (unsigned)f2bf(a[2] * iv) | ((unsigned)f2bf(a[3] * iv) << 16);
                    o.z = (unsigned)f2bf(a[4] * iv) | ((unsigned)f2bf(a[5] * iv) << 16);
                    o.w = (unsigned)f2bf(a[6] * iv) | ((unsigned)f2bf(a[7] * iv) << 16);
                    *(uint4*)(sA + rows[t] * 136 + li * 8) = o;
                }
            }
        }
        __syncthreads();

        // ---- phase 2: dual MFMA, wave = 32 rows x 32 cols (nt0 = wave*2) ----
        const int m = lane & 15;
        const int q = lane >> 4;
        const int nt0 = wave * 2;
        const int rg0 = min(nb0 + m,      n - 1);
        const int rg1 = min(nb0 + 16 + m, n - 1);

        f4v acc[2][2];
        #pragma unroll
        for (int mt = 0; mt < 2; mt++)
            #pragma unroll
            for (int c = 0; c < 2; c++) {
                acc[mt][c][0] = 0.f; acc[mt][c][1] = 0.f; acc[mt][c][2] = 0.f; acc[mt][c][3] = 0.f;
            }

        #pragma unroll
        for (int kt = 0; kt < 4; kt++) {
            const int ko = kt * 32 + q * 8;
            s8v a0 = *(const s8v*)(sA + m * 136 + ko);                // agg side (LDS)
            s8v a1 = *(const s8v*)(sA + (16 + m) * 136 + ko);
            s8v a0d = *(const s8v*)(feat + (size_t)rg0 * 128 + ko);   // root side (global)
            s8v a1d = *(const s8v*)(feat + (size_t)rg1 * 128 + ko);
            #pragma unroll
            for (int c = 0; c < 2; c++) {
                s8v b  = *(const s8v*)(Bl + ((size_t)(kt * 8 + nt0 + c) * 64 + lane) * 8);
                acc[0][c] = __builtin_amdgcn_mfma_f32_16x16x32_bf16(a0, b, acc[0][c], 0, 0, 0);
                acc[1][c] = __builtin_amdgcn_mfma_f32_16x16x32_bf16(a1, b, acc[1][c], 0, 0, 0);
                s8v b2 = *(const s8v*)(Br + ((size_t)(kt * 8 + nt0 + c) * 64 + lane) * 8);
                acc[0][c] = __builtin_amdgcn_mfma_f32_16x16x32_bf16(a0d, b2, acc[0][c], 0, 0, 0);
                acc[1][c] = __builtin_amdgcn_mfma_f32_16x16x32_bf16(a1d, b2, acc[1][c], 0, 0, 0);
            }
        }

        // ---- epilogue: BN+ReLU, write bf16 (and stash tile for t3) ---------
        float scv[2], shv[2];
        #pragma unroll
        for (int c = 0; c < 2; c++) {
            int col = (nt0 + c) * 16 + m;
            scv[c] = scale[col]; shv[c] = shift[col];
        }
        #pragma unroll
        for (int mt = 0; mt < 2; mt++) {
            #pragma unroll
            for (int reg = 0; reg < 4; reg++) {
                int rloc = mt * 16 + q * 4 + reg;
                int row  = nb0 + rloc;
                if (row < n) {
                    #pragma unroll
                    for (int c = 0; c < 2; c++) {
                        int col = (nt0 + c) * 16 + m;
                        float v = fmaxf(acc[mt][c][reg] * scv[c] + shv[c], 0.f);
                        unsigned short uq = f2bf(v);
                        out[(size_t)row * 128 + col] = uq;
                        if constexpr (T3) sH[rloc * 136 + col] = uq;
                    }
                }
            }
        }

        // ---- phase 3 (layer 2 only): t3 = hb2_tile @ Wl3, wave = 16 cols ---
        if constexpr (T3) {
            __syncthreads();
            f4v a3c[2];
            #pragma unroll
            for (int mt = 0; mt < 2; mt++) { a3c[mt][0] = 0.f; a3c[mt][1] = 0.f; a3c[mt][2] = 0.f; a3c[mt][3] = 0.f; }
            #pragma unroll
            for (int kt = 0; kt < 4; kt++) {
                const int ko = kt * 32 + q * 8;
                s8v a0 = *(const s8v*)(sH + m * 136 + ko);
                s8v a1 = *(const s8v*)(sH + (16 + m) * 136 + ko);
                s8v b  = *(const s8v*)(W3p + ((size_t)(kt * 4 + wave) * 64 + lane) * 8);
                a3c[0] = __builtin_amdgcn_mfma_f32_16x16x32_bf16(a0, b, a3c[0], 0, 0, 0);
                a3c[1] = __builtin_amdgcn_mfma_f32_16x16x32_bf16(a1, b, a3c[1], 0, 0, 0);
            }
            #pragma unroll
            for (int mt = 0; mt < 2; mt++) {
                #pragma unroll
                for (int reg = 0; reg < 4; reg++) {
                    int row = nb0 + mt * 16 + q * 4 + reg;
                    if (row < n) t3[(size_t)row * 64 + wave * 16 + m] = f2bf(a3c[mt][reg]);
                }
            }
        }
        __syncthreads();   // protect sA/sH before next unit's gather
    }
}

// ---- fused layer 3: gather-mean(t3) + hb2@Wr3 + bias -----------------------
__global__ __launch_bounds__(256) void k_final(const unsigned short* __restrict__ hb2,
                                               const unsigned short* __restrict__ t3,
                                               const int* __restrict__ cnt, const int* __restrict__ bucket,
                                               const unsigned short* __restrict__ Bp, const float* __restrict__ bias,
                                               float* __restrict__ outf, int n, int units) {
    __shared__ float sG[32 * 68];   // fp32 agg tile, stride 68 floats
    const int tid  = threadIdx.x;
    const int wave = tid >> 6;
    const int lane = tid & 63;

    for (int u = blockIdx.x; u < units; u += gridDim.x) {
        const int nb0 = u * 32;

        // ---- phase 1: gather-mean ------------------------------------------
        {
            const int e8   = lane >> 3;
            const int li   = lane & 7;
            const int base = e8 << 3;
            const uint4* inp = (const uint4*)t3;       // 128B row = 8 x uint4
            const int row  = wave * 8 + e8;
            const int node = nb0 + row;
            const bool ok  = node < n;
            int c = ok ? cnt[node] : 0; if (c > CAP) c = CAP;
            int idx1 = (ok && li < c)     ? bucket[(size_t)node * CAP + li]     : n;
            int idx2 = (ok && li + 8 < c) ? bucket[(size_t)node * CAP + li + 8] : n;
            float a[8] = {0.f, 0.f, 0.f, 0.f, 0.f, 0.f, 0.f, 0.f};
            if (c > 0) {
                #pragma unroll
                for (int uu = 0; uu < 8; uu++) {
                    int idx = __shfl(idx1, base + uu);
                    uint4 v = inp[(size_t)idx * 8 + li];
                    ACC8(a, v);
                }
            }
            if (c > 8) {
                #pragma unroll
                for (int uu = 0; uu < 8; uu++) {
                    int idx = __shfl(idx2, base + uu);
                    uint4 v = inp[(size_t)idx * 8 + li];
                    ACC8(a, v);
                }
            }
            for (int s = 16; s < c; s++) {             // deg>16 (rare)
                int idx = bucket[(size_t)node * CAP + s];
                uint4 v = inp[(size_t)idx * 8 + li];
                ACC8(a, v);
            }
            if (ok) {
                float iv = 1.0f / fmaxf((float)c, 1.0f);
                float4 o1; o1.x = a[0] * iv; o1.y = a[1] * iv; o1.z = a[2] * iv; o1.w = a[3] * iv;
                float4 o2; o2.x = a[4] * iv; o2.y = a[5] * iv; o2.z = a[6] * iv; o2.w = a[7] * iv;
                *(float4*)(sG + row * 68 + li * 8)     = o1;
                *(float4*)(sG + row * 68 + li * 8 + 4) = o2;
            }
        }
        __syncthreads();

        // ---- phase 2: out = hb2 @ Wr3 + agg + bias --------------------------
        const int m = lane & 15;
        const int q = lane >> 4;
        const int rg0 = min(nb0 + m,      n - 1);
        const int rg1 = min(nb0 + 16 + m, n - 1);

        f4v acc[2];
        #pragma unroll
        for (int mt = 0; mt < 2; mt++) { acc[mt][0] = 0.f; acc[mt][1] = 0.f; acc[mt][2] = 0.f; acc[mt][3] = 0.f; }

        #pragma unroll
        for (int kt = 0; kt < 4; kt++) {
            const int ko = kt * 32 + q * 8;
            s8v a0 = *(const s8v*)(hb2 + (size_t)rg0 * 128 + ko);
            s8v a1 = *(const s8v*)(hb2 + (size_t)rg1 * 128 + ko);
            s8v b  = *(const s8v*)(Bp + ((size_t)(kt * 4 + wave) * 64 + lane) * 8);
            acc[0] = __builtin_amdgcn_mfma_f32_16x16x32_bf16(a0, b, acc[0], 0, 0, 0);
            acc[1] = __builtin_amdgcn_mfma_f32_16x16x32_bf16(a1, b, acc[1], 0, 0, 0);
        }

        const int col = wave * 16 + m;
        const float bv = bias[col];
        #pragma unroll
        for (int mt = 0; mt < 2; mt++) {
            #pragma unroll
            for (int reg = 0; reg < 4; reg++) {
                int rloc = mt * 16 + q * 4 + reg;
                int row  = nb0 + rloc;
                if (row < n) outf[(size_t)row * 64 + col] = acc[mt][reg] + sG[rloc * 68 + col] + bv;
            }
        }
        __syncthreads();   // protect sG before next unit's gather
    }
}

extern "C" void kernel_launch(void* const* d_in, const int* in_sizes, int n_in,
                              void* d_out, int out_size, void* d_ws, size_t ws_size,
                              hipStream_t stream) {
    const float* x   = (const float*)d_in[0];
    const int*   ei  = (const int*)d_in[1];
    const float* Wl1 = (const float*)d_in[2];
    const float* bl1 = (const float*)d_in[3];
    const float* Wr1 = (const float*)d_in[4];
    const float* g1  = (const float*)d_in[5];
    const float* be1 = (const float*)d_in[6];
    const float* rm1 = (const float*)d_in[7];
    const float* rv1 = (const float*)d_in[8];
    const float* Wl2 = (const float*)d_in[9];
    const float* bl2 = (const float*)d_in[10];
    const float* Wr2 = (const float*)d_in[11];
    const float* g2  = (const float*)d_in[12];
    const float* be2 = (const float*)d_in[13];
    const float* rm2 = (const float*)d_in[14];
    const float* rv2 = (const float*)d_in[15];
    const float* Wl3 = (const float*)d_in[16];
    const float* bl3 = (const float*)d_in[17];
    const float* Wr3 = (const float*)d_in[18];

    const int N = in_sizes[0] / 128;
    const int E = in_sizes[1] / 2;
    const int* src = ei;
    const int* dst = ei + E;

    // workspace layout (feature buffers have N+1 rows; row N is the zero row)
    char* w = (char*)d_ws;
    auto au = [](size_t v) { return (v + 1023) & ~(size_t)1023; };
    size_t off = 0;
    int*            cnt    = (int*)(w + off);            off += au((size_t)N * 4);
    int*            bucket = (int*)(w + off);            off += au((size_t)N * CAP * 4);
    unsigned short* xb     = (unsigned short*)(w + off); off += au((size_t)(N + 1) * 128 * 2);
    unsigned short* hb     = (unsigned short*)(w + off); off += au((size_t)(N + 1) * 128 * 2);
    unsigned short* hb2    = (unsigned short*)(w + off); off += au((size_t)(N + 1) * 128 * 2);
    unsigned short* t3b    = (unsigned short*)(w + off); off += au((size_t)(N + 1) * 64 * 2);
    unsigned short* Wp[6];
    Wp[0] = (unsigned short*)(w + off); off += au(128 * 128 * 2);  // Wl1
    Wp[1] = (unsigned short*)(w + off); off += au(128 * 128 * 2);  // Wr1
    Wp[2] = (unsigned short*)(w + off); off += au(128 * 128 * 2);  // Wl2
    Wp[3] = (unsigned short*)(w + off); off += au(128 * 128 * 2);  // Wr2
    Wp[4] = (unsigned short*)(w + off); off += au(128 * 64 * 2);   // Wl3
    Wp[5] = (unsigned short*)(w + off); off += au(128 * 64 * 2);   // Wr3
    float* P = (float*)(w + off); off += 2048;
    (void)ws_size; (void)n_in;

    hipMemsetAsync(cnt, 0, (size_t)N * 4, stream);

    const int n4 = N * 32;
    const int nbBucket = (E + 255) / 256;
    const int nbCvt    = (n4 + 255) / 256;
    k_prep<<<nbBucket + nbCvt + 448, 256, 0, stream>>>(src, dst, E, cnt, bucket,
                                                       x, xb, n4,
                                                       Wl1, Wr1, Wl2, Wr2, Wl3, Wr3,
                                                       Wp[0], Wp[1], Wp[2], Wp[3], Wp[4], Wp[5],
                                                       g1, be1, rm1, rv1, bl1, g2, be2, rm2, rv2, bl2, P,
                                                       hb, hb2, t3b, N, nbBucket, nbCvt);

    const int units = (N + 31) / 32;
    const int grid  = (units + 1) / 2;     // persistent: each block does 2 units

    // layer 1: hb = relu(bn(agg(x)@Wl1 + bl1 + x@Wr1))
    k_fused<false><<<grid, 256, 0, stream>>>(xb, cnt, bucket, Wp[0], Wp[1],
                                             P, P + 128, hb, nullptr, nullptr, N, units);
    // layer 2: hb2 = relu(bn(agg(hb)@Wl2 + bl2 + hb@Wr2)); t3b = hb2@Wl3
    k_fused<true><<<grid, 256, 0, stream>>>(hb, cnt, bucket, Wp[2], Wp[3],
                                            P + 256, P + 384, hb2, Wp[4], t3b, N, units);
    // layer 3: out = agg(t3b) + hb2@Wr3 + bl3
    k_final<<<grid, 256, 0, stream>>>(hb2, t3b, cnt, bucket, Wp[5], bl3, (float*)d_out, N, units);
}

// Round 5
// 299.720 us; speedup vs baseline: 2.9412x; 1.0185x over previous
//
#include <hip/hip_runtime.h>

#define CAP 48

typedef short  s8v  __attribute__((ext_vector_type(8)));
typedef float  f4v  __attribute__((ext_vector_type(4)));

__device__ __forceinline__ unsigned short f2bf(float f) {
    unsigned u = __float_as_uint(f);
    u += 0x7FFFu + ((u >> 16) & 1u);      // RNE
    return (unsigned short)(u >> 16);
}
__device__ __forceinline__ float bflo(unsigned v) { return __uint_as_float(v << 16); }
__device__ __forceinline__ float bfhi(unsigned v) { return __uint_as_float(v & 0xffff0000u); }

#define ACC8(A_, v) do { (A_)[0]+=bflo((v).x); (A_)[1]+=bfhi((v).x); (A_)[2]+=bflo((v).y); (A_)[3]+=bfhi((v).y); \
                         (A_)[4]+=bflo((v).z); (A_)[5]+=bfhi((v).z); (A_)[6]+=bflo((v).w); (A_)[7]+=bfhi((v).w); } while(0)

// ---- merged prep: bucket CSR + x->bf16 convert + weight pack + BN fold -----
__global__ __launch_bounds__(256) void k_prep(const int* __restrict__ src, const int* __restrict__ dst, int E,
                                              int* __restrict__ cnt, int* __restrict__ bucket,
                                              const float* __restrict__ x, unsigned short* __restrict__ xb, int n4,
                                              const float* W0, const float* W1, const float* W2,
                                              const float* W3, const float* W4, const float* W5,
                                              unsigned short* P0, unsigned short* P1, unsigned short* P2,
                                              unsigned short* P3, unsigned short* P4, unsigned short* P5,
                                              const float* g1, const float* be1, const float* rm1, const float* rv1, const float* bl1,
                                              const float* g2, const float* be2, const float* rm2, const float* rv2, const float* bl2,
                                              float* P,
                                              unsigned short* hb, unsigned short* hb2, unsigned short* t3b, int N,
                                              int nbBucket, int nbCvt) {
    int b = blockIdx.x;
    const int tid = threadIdx.x;
    if (b < nbBucket) {
        int e = b * 256 + tid;
        if (e < E) {
            int d = dst[e];
            int slot = atomicAdd(&cnt[d], 1);
            if (slot < CAP) bucket[(size_t)d * CAP + slot] = src[e];
        }
        return;
    }
    b -= nbBucket;
    if (b < nbCvt) {
        int i = b * 256 + tid;
        if (i < n4) {
            float4 v = ((const float4*)x)[i];
            ushort4 o;
            o.x = f2bf(v.x); o.y = f2bf(v.y); o.z = f2bf(v.z); o.w = f2bf(v.w);
            ((ushort4*)xb)[i] = o;
        }
        return;
    }
    b -= nbCvt;
    const int px = b & 63;
    const int py = b >> 6;
    if (py == 6) {
        if (px == 0 && tid < 128) {
            int i = tid;
            float s1 = g1[i] * rsqrtf(rv1[i] + 1e-5f);
            P[i]       = s1;
            P[128 + i] = (bl1[i] - rm1[i]) * s1 + be1[i];
            float s2 = g2[i] * rsqrtf(rv2[i] + 1e-5f);
            P[256 + i] = s2;
            P[384 + i] = (bl2[i] - rm2[i]) * s2 + be2[i];
            // zero row N of each feature buffer (gather padding target)
            xb [(size_t)N * 128 + i] = 0;
            hb [(size_t)N * 128 + i] = 0;
            hb2[(size_t)N * 128 + i] = 0;
            if (i < 64) t3b[(size_t)N * 64 + i] = 0;
        }
        return;
    }
    const float* W; unsigned short* Pk; int JD;
    switch (py) {
        case 0: W = W0; Pk = P0; JD = 128; break;
        case 1: W = W1; Pk = P1; JD = 128; break;
        case 2: W = W2; Pk = P2; JD = 128; break;
        case 3: W = W3; Pk = P3; JD = 128; break;
        case 4: W = W4; Pk = P4; JD = 64;  break;
        default:W = W5; Pk = P5; JD = 64;  break;
    }
    int o = px * 256 + tid;
    if (o >= 128 * JD) return;
    int j    = o & 7;
    int lane = (o >> 3) & 63;
    int t    = o >> 9;
    int nt   = t % (JD / 16);
    int kt   = t / (JD / 16);
    int k = kt * 32 + (lane >> 4) * 8 + j;
    int nn = nt * 16 + (lane & 15);
    Pk[o] = f2bf(W[(size_t)k * JD + nn]);
}

// ---- fused SAGE layer: wave-independent, barrier-free ----------------------
// block = 64 nodes, 4 waves; each wave owns 16 nodes end-to-end:
//   gather-mean (quarter-wave per node, 4 serial slots) -> own LDS quarter,
//   16x128 dual MFMA (8 col-tiles), BN+ReLU epilogue,
//   (T3) hb2 tile written back into own sA region, then 16x64 t3 MFMA.
// No __syncthreads anywhere -> no inter-wave imbalance coupling.
template<bool T3>
__global__ __launch_bounds__(256) void k_fused(const unsigned short* __restrict__ feat,
                                               const int* __restrict__ cnt, const int* __restrict__ bucket,
                                               const unsigned short* __restrict__ Bl, const unsigned short* __restrict__ Br,
                                               const float* __restrict__ scale, const float* __restrict__ shift,
                                               unsigned short* __restrict__ out,
                                               const unsigned short* __restrict__ W3p, unsigned short* __restrict__ t3,
                                               int n) {
    __shared__ unsigned short sA[64 * 136];
    const int tid  = threadIdx.x;
    const int wave = tid >> 6;
    const int lane = tid & 63;
    const int nb0  = blockIdx.x * 64;
    const int wb   = nb0 + wave * 16;          // wave's first node
    if (wb >= n) return;                        // whole-wave OOB (uniform per wave)

    // ---- phase 1: gather-mean (own LDS quarter, 4 slots) -------------------
    {
        const int q4   = lane >> 4;
        const int li   = lane & 15;
        const int base = q4 << 4;
        const uint4* inp = (const uint4*)feat;     // 256B row = 16 x uint4
        int cs[4], idxs[4];
        #pragma unroll
        for (int t = 0; t < 4; t++) {
            int node = wb + t * 4 + q4;
            bool ok = node < n;
            int c = ok ? cnt[node] : 0; if (c > CAP) c = CAP;
            cs[t] = c;
            idxs[t] = (ok && li < c) ? bucket[(size_t)node * CAP + li] : n;  // n = zero row
        }
        #pragma unroll
        for (int t = 0; t < 4; t++) {
            const int c = cs[t];
            float a[8] = {0.f, 0.f, 0.f, 0.f, 0.f, 0.f, 0.f, 0.f};
            if (c > 0) {
                #pragma unroll
                for (int uu = 0; uu < 8; uu++) {
                    int idx = __shfl(idxs[t], base + uu);       // >=c lanes hold n (zero row)
                    uint4 v = inp[(size_t)idx * 16 + li];
                    ACC8(a, v);
                }
            }
            if (c > 8) {
                #pragma unroll
                for (int uu = 8; uu < 16; uu++) {
                    int idx = __shfl(idxs[t], base + uu);
                    uint4 v = inp[(size_t)idx * 16 + li];
                    ACC8(a, v);
                }
            }
            const int node = wb + t * 4 + q4;
            for (int s = 16; s < c; s++) {                      // deg>16 (rare)
                int idx = bucket[(size_t)node * CAP + s];
                uint4 v = inp[(size_t)idx * 16 + li];
                ACC8(a, v);
            }
            if (node < n) {
                float iv = 1.0f / fmaxf((float)c, 1.0f);
                uint4 o;
                o.x = (unsigned)f2bf(a[0] * iv) | ((unsigned)f2bf(a[1] * iv) << 16);
                o.y = (unsigned)f2bf(a[2] * iv) | ((unsigned)f2bf(a[3] * iv) << 16);
                o.z = (unsigned)f2bf(a[4] * iv) | ((unsigned)f2bf(a[5] * iv) << 16);
                o.w = (unsigned)f2bf(a[6] * iv) | ((unsigned)f2bf(a[7] * iv) << 16);
                *(uint4*)(sA + (wave * 16 + t * 4 + q4) * 136 + li * 8) = o;
            }
        }
    }
    // no barrier: this wave wrote its own rows, reads its own rows below

    // ---- phase 2: 16 rows x 128 cols dual MFMA ------------------------------
    const int m = lane & 15;
    const int q = lane >> 4;
    const int arow = wave * 16 + m;
    const int rg = min(wb + m, n - 1);

    f4v acc[8];
    #pragma unroll
    for (int nt = 0; nt < 8; nt++) { acc[nt][0] = 0.f; acc[nt][1] = 0.f; acc[nt][2] = 0.f; acc[nt][3] = 0.f; }

    #pragma unroll
    for (int kt = 0; kt < 4; kt++) {
        const int ko = kt * 32 + q * 8;
        s8v a0  = *(const s8v*)(sA + arow * 136 + ko);            // agg side (LDS)
        s8v a0d = *(const s8v*)(feat + (size_t)rg * 128 + ko);    // root side (global)
        #pragma unroll
        for (int nt = 0; nt < 8; nt++) {
            s8v b  = *(const s8v*)(Bl + ((size_t)(kt * 8 + nt) * 64 + lane) * 8);
            acc[nt] = __builtin_amdgcn_mfma_f32_16x16x32_bf16(a0, b, acc[nt], 0, 0, 0);
            s8v b2 = *(const s8v*)(Br + ((size_t)(kt * 8 + nt) * 64 + lane) * 8);
            acc[nt] = __builtin_amdgcn_mfma_f32_16x16x32_bf16(a0d, b2, acc[nt], 0, 0, 0);
        }
    }

    // ---- epilogue: BN+ReLU, write bf16 (T3: stash hb2 back into own sA) ----
    #pragma unroll
    for (int nt = 0; nt < 8; nt++) {
        const int col = nt * 16 + m;
        const float sc = scale[col];
        const float sh = shift[col];
        #pragma unroll
        for (int reg = 0; reg < 4; reg++) {
            int rloc = wave * 16 + q * 4 + reg;
            int row  = nb0 + rloc;
            if (row < n) {
                float v = fmaxf(acc[nt][reg] * sc + sh, 0.f);
                unsigned short uq = f2bf(v);
                out[(size_t)row * 128 + col] = uq;
                if constexpr (T3) sA[rloc * 136 + col] = uq;
            }
        }
    }

    // ---- phase 3 (layer 2 only): t3 = hb2_tile @ Wl3 (own rows) ------------
    if constexpr (T3) {
        f4v a3c[4];
        #pragma unroll
        for (int nt = 0; nt < 4; nt++) { a3c[nt][0] = 0.f; a3c[nt][1] = 0.f; a3c[nt][2] = 0.f; a3c[nt][3] = 0.f; }
        #pragma unroll
        for (int kt = 0; kt < 4; kt++) {
            const int ko = kt * 32 + q * 8;
            s8v a0 = *(const s8v*)(sA + arow * 136 + ko);
            #pragma unroll
            for (int nt = 0; nt < 4; nt++) {
                s8v b = *(const s8v*)(W3p + ((size_t)(kt * 4 + nt) * 64 + lane) * 8);
                a3c[nt] = __builtin_amdgcn_mfma_f32_16x16x32_bf16(a0, b, a3c[nt], 0, 0, 0);
            }
        }
        #pragma unroll
        for (int nt = 0; nt < 4; nt++) {
            #pragma unroll
            for (int reg = 0; reg < 4; reg++) {
                int row = nb0 + wave * 16 + q * 4 + reg;
                if (row < n) t3[(size_t)row * 64 + nt * 16 + m] = f2bf(a3c[nt][reg]);
            }
        }
    }
}

// ---- fused layer 3: wave-independent gather-mean(t3) + hb2@Wr3 + bias ------
// block = 64 nodes, 4 waves; wave owns 16 nodes: gather (eighth-wave per node,
// 2 serial slots) -> own sG quarter; 16x64 MFMA; add agg + bias; no barriers.
__global__ __launch_bounds__(256) void k_final(const unsigned short* __restrict__ hb2,
                                               const unsigned short* __restrict__ t3,
                                               const int* __restrict__ cnt, const int* __restrict__ bucket,
                                               const unsigned short* __restrict__ Bp, const float* __restrict__ bias,
                                               float* __restrict__ outf, int n) {
    __shared__ float sG[64 * 68];   // fp32 agg tile, stride 68 floats
    const int tid  = threadIdx.x;
    const int wave = tid >> 6;
    const int lane = tid & 63;
    const int nb0  = blockIdx.x * 64;
    const int wb   = nb0 + wave * 16;
    if (wb >= n) return;

    // ---- phase 1: gather-mean (own sG quarter, 2 slots) --------------------
    {
        const int e8   = lane >> 3;
        const int li   = lane & 7;
        const int base = e8 << 3;
        const uint4* inp = (const uint4*)t3;       // 128B row = 8 x uint4
        #pragma unroll
        for (int t = 0; t < 2; t++) {
            const int trow = t * 8 + e8;
            const int node = wb + trow;
            const bool ok  = node < n;
            int c = ok ? cnt[node] : 0; if (c > CAP) c = CAP;
            int idx1 = (ok && li < c)     ? bucket[(size_t)node * CAP + li]     : n;
            int idx2 = (ok && li + 8 < c) ? bucket[(size_t)node * CAP + li + 8] : n;
            float a[8] = {0.f, 0.f, 0.f, 0.f, 0.f, 0.f, 0.f, 0.f};
            if (c > 0) {
                #pragma unroll
                for (int uu = 0; uu < 8; uu++) {
                    int idx = __shfl(idx1, base + uu);
                    uint4 v = inp[(size_t)idx * 8 + li];
                    ACC8(a, v);
                }
            }
            if (c > 8) {
                #pragma unroll
                for (int uu = 0; uu < 8; uu++) {
                    int idx = __shfl(idx2, base + uu);
                    uint4 v = inp[(size_t)idx * 8 + li];
                    ACC8(a, v);
                }
            }
            for (int s = 16; s < c; s++) {             // deg>16 (rare)
                int idx = bucket[(size_t)node * CAP + s];
                uint4 v = inp[(size_t)idx * 8 + li];
                ACC8(a, v);
            }
            if (ok) {
                float iv = 1.0f / fmaxf((float)c, 1.0f);
                float4 o1; o1.x = a[0] * iv; o1.y = a[1] * iv; o1.z = a[2] * iv; o1.w = a[3] * iv;
                float4 o2; o2.x = a[4] * iv; o2.y = a[5] * iv; o2.z = a[6] * iv; o2.w = a[7] * iv;
                *(float4*)(sG + (wave * 16 + trow) * 68 + li * 8)     = o1;
                *(float4*)(sG + (wave * 16 + trow) * 68 + li * 8 + 4) = o2;
            }
        }
    }
    // no barrier: own quarter only

    // ---- phase 2: out = hb2 @ Wr3 + agg + bias ------------------------------
    const int m = lane & 15;
    const int q = lane >> 4;
    const int rg = min(wb + m, n - 1);

    f4v acc[4];
    #pragma unroll
    for (int nt = 0; nt < 4; nt++) { acc[nt][0] = 0.f; acc[nt][1] = 0.f; acc[nt][2] = 0.f; acc[nt][3] = 0.f; }

    #pragma unroll
    for (int kt = 0; kt < 4; kt++) {
        const int ko = kt * 32 + q * 8;
        s8v a0 = *(const s8v*)(hb2 + (size_t)rg * 128 + ko);
        #pragma unroll
        for (int nt = 0; nt < 4; nt++) {
            s8v b = *(const s8v*)(Bp + ((size_t)(kt * 4 + nt) * 64 + lane) * 8);
            acc[nt] = __builtin_amdgcn_mfma_f32_16x16x32_bf16(a0, b, acc[nt], 0, 0, 0);
        }
    }

    #pragma unroll
    for (int nt = 0; nt < 4; nt++) {
        const int col = nt * 16 + m;
        const float bv = bias[col];
        #pragma unroll
        for (int reg = 0; reg < 4; reg++) {
            int rloc = wave * 16 + q * 4 + reg;
            int row  = nb0 + rloc;
            if (row < n) outf[(size_t)row * 64 + col] = acc[nt][reg] + sG[rloc * 68 + col] + bv;
        }
    }
}

extern "C" void kernel_launch(void* const* d_in, const int* in_sizes, int n_in,
                              void* d_out, int out_size, void* d_ws, size_t ws_size,
                              hipStream_t stream) {
    const float* x   = (const float*)d_in[0];
    const int*   ei  = (const int*)d_in[1];
    const float* Wl1 = (const float*)d_in[2];
    const float* bl1 = (const float*)d_in[3];
    const float* Wr1 = (const float*)d_in[4];
    const float* g1  = (const float*)d_in[5];
    const float* be1 = (const float*)d_in[6];
    const float* rm1 = (const float*)d_in[7];
    const float* rv1 = (const float*)d_in[8];
    const float* Wl2 = (const float*)d_in[9];
    const float* bl2 = (const float*)d_in[10];
    const float* Wr2 = (const float*)d_in[11];
    const float* g2  = (const float*)d_in[12];
    const float* be2 = (const float*)d_in[13];
    const float* rm2 = (const float*)d_in[14];
    const float* rv2 = (const float*)d_in[15];
    const float* Wl3 = (const float*)d_in[16];
    const float* bl3 = (const float*)d_in[17];
    const float* Wr3 = (const float*)d_in[18];

    const int N = in_sizes[0] / 128;
    const int E = in_sizes[1] / 2;
    const int* src = ei;
    const int* dst = ei + E;

    // workspace layout (feature buffers have N+1 rows; row N is the zero row)
    char* w = (char*)d_ws;
    auto au = [](size_t v) { return (v + 1023) & ~(size_t)1023; };
    size_t off = 0;
    int*            cnt    = (int*)(w + off);            off += au((size_t)N * 4);
    int*            bucket = (int*)(w + off);            off += au((size_t)N * CAP * 4);
    unsigned short* xb     = (unsigned short*)(w + off); off += au((size_t)(N + 1) * 128 * 2);
    unsigned short* hb     = (unsigned short*)(w + off); off += au((size_t)(N + 1) * 128 * 2);
    unsigned short* hb2    = (unsigned short*)(w + off); off += au((size_t)(N + 1) * 128 * 2);
    unsigned short* t3b    = (unsigned short*)(w + off); off += au((size_t)(N + 1) * 64 * 2);
    unsigned short* Wp[6];
    Wp[0] = (unsigned short*)(w + off); off += au(128 * 128 * 2);  // Wl1
    Wp[1] = (unsigned short*)(w + off); off += au(128 * 128 * 2);  // Wr1
    Wp[2] = (unsigned short*)(w + off); off += au(128 * 128 * 2);  // Wl2
    Wp[3] = (unsigned short*)(w + off); off += au(128 * 128 * 2);  // Wr2
    Wp[4] = (unsigned short*)(w + off); off += au(128 * 64 * 2);   // Wl3
    Wp[5] = (unsigned short*)(w + off); off += au(128 * 64 * 2);   // Wr3
    float* P = (float*)(w + off); off += 2048;
    (void)ws_size; (void)n_in;

    hipMemsetAsync(cnt, 0, (size_t)N * 4, stream);

    const int n4 = N * 32;
    const int nbBucket = (E + 255) / 256;
    const int nbCvt    = (n4 + 255) / 256;
    k_prep<<<nbBucket + nbCvt + 448, 256, 0, stream>>>(src, dst, E, cnt, bucket,
                                                       x, xb, n4,
                                                       Wl1, Wr1, Wl2, Wr2, Wl3, Wr3,
                                                       Wp[0], Wp[1], Wp[2], Wp[3], Wp[4], Wp[5],
                                                       g1, be1, rm1, rv1, bl1, g2, be2, rm2, rv2, bl2, P,
                                                       hb, hb2, t3b, N, nbBucket, nbCvt);

    const int grid = (N + 63) / 64;

    // layer 1: hb = relu(bn(agg(x)@Wl1 + bl1 + x@Wr1))
    k_fused<false><<<grid, 256, 0, stream>>>(xb, cnt, bucket, Wp[0], Wp[1],
                                             P, P + 128, hb, nullptr, nullptr, N);
    // layer 2: hb2 = relu(bn(agg(hb)@Wl2 + bl2 + hb@Wr2)); t3b = hb2@Wl3
    k_fused<true><<<grid, 256, 0, stream>>>(hb, cnt, bucket, Wp[2], Wp[3],
                                            P + 256, P + 384, hb2, Wp[4], t3b, N);
    // layer 3: out = agg(t3b) + hb2@Wr3 + bl3
    k_final<<<grid, 256, 0, stream>>>(hb2, t3b, cnt, bucket, Wp[5], bl3, (float*)d_out, N);
}

// Round 6
// 287.486 us; speedup vs baseline: 3.0664x; 1.0426x over previous
//
#include <hip/hip_runtime.h>

#define CAP 48

typedef short  s8v  __attribute__((ext_vector_type(8)));
typedef float  f4v  __attribute__((ext_vector_type(4)));

__device__ __forceinline__ unsigned short f2bf(float f) {
    unsigned u = __float_as_uint(f);
    u += 0x7FFFu + ((u >> 16) & 1u);      // RNE
    return (unsigned short)(u >> 16);
}
__device__ __forceinline__ float bflo(unsigned v) { return __uint_as_float(v << 16); }
__device__ __forceinline__ float bfhi(unsigned v) { return __uint_as_float(v & 0xffff0000u); }

#define ACC8(v)  do { a[0]+=bflo((v).x); a[1]+=bfhi((v).x); a[2]+=bflo((v).y); a[3]+=bfhi((v).y); \
                      a[4]+=bflo((v).z); a[5]+=bfhi((v).z); a[6]+=bflo((v).w); a[7]+=bfhi((v).w); } while(0)

// ---- merged prep: bucket CSR + x->bf16 convert + weight pack + BN fold -----
// blocks [0, nbBucket)               : edge bucketing
// blocks [nbBucket, nbBucket+nbCvt)  : fp32 -> bf16 convert of x
// blocks [nbBucket+nbCvt, +448)      : weight prepack (64 x 7 grid linearized)
__global__ __launch_bounds__(256) void k_prep(const int* __restrict__ src, const int* __restrict__ dst, int E,
                                              int* __restrict__ cnt, int* __restrict__ bucket,
                                              const float* __restrict__ x, unsigned short* __restrict__ xb, int n4,
                                              const float* W0, const float* W1, const float* W2,
                                              const float* W3, const float* W4, const float* W5,
                                              unsigned short* P0, unsigned short* P1, unsigned short* P2,
                                              unsigned short* P3, unsigned short* P4, unsigned short* P5,
                                              const float* g1, const float* be1, const float* rm1, const float* rv1, const float* bl1,
                                              const float* g2, const float* be2, const float* rm2, const float* rv2, const float* bl2,
                                              float* P,
                                              unsigned short* hb, unsigned short* hb2, unsigned short* t3b, int N,
                                              int nbBucket, int nbCvt) {
    int b = blockIdx.x;
    const int tid = threadIdx.x;
    if (b < nbBucket) {
        int e = b * 256 + tid;
        if (e < E) {
            int d = dst[e];
            int slot = atomicAdd(&cnt[d], 1);
            if (slot < CAP) bucket[(size_t)d * CAP + slot] = src[e];
        }
        return;
    }
    b -= nbBucket;
    if (b < nbCvt) {
        int i = b * 256 + tid;
        if (i < n4) {
            float4 v = ((const float4*)x)[i];
            ushort4 o;
            o.x = f2bf(v.x); o.y = f2bf(v.y); o.z = f2bf(v.z); o.w = f2bf(v.w);
            ((ushort4*)xb)[i] = o;
        }
        return;
    }
    b -= nbCvt;
    const int px = b & 63;
    const int py = b >> 6;
    if (py == 6) {
        if (px == 0 && tid < 128) {
            int i = tid;
            float s1 = g1[i] * rsqrtf(rv1[i] + 1e-5f);
            P[i]       = s1;
            P[128 + i] = (bl1[i] - rm1[i]) * s1 + be1[i];
            float s2 = g2[i] * rsqrtf(rv2[i] + 1e-5f);
            P[256 + i] = s2;
            P[384 + i] = (bl2[i] - rm2[i]) * s2 + be2[i];
            // zero row N of each feature buffer (gather padding target)
            xb [(size_t)N * 128 + i] = 0;
            hb [(size_t)N * 128 + i] = 0;
            hb2[(size_t)N * 128 + i] = 0;
            if (i < 64) t3b[(size_t)N * 64 + i] = 0;
        }
        return;
    }
    const float* W; unsigned short* Pk; int JD;
    switch (py) {
        case 0: W = W0; Pk = P0; JD = 128; break;
        case 1: W = W1; Pk = P1; JD = 128; break;
        case 2: W = W2; Pk = P2; JD = 128; break;
        case 3: W = W3; Pk = P3; JD = 128; break;
        case 4: W = W4; Pk = P4; JD = 64;  break;
        default:W = W5; Pk = P5; JD = 64;  break;
    }
    int o = px * 256 + tid;
    if (o >= 128 * JD) return;
    int j    = o & 7;
    int lane = (o >> 3) & 63;
    int t    = o >> 9;
    int nt   = t % (JD / 16);
    int kt   = t / (JD / 16);
    int k = kt * 32 + (lane >> 4) * 8 + j;
    int nn = nt * 16 + (lane & 15);
    Pk[o] = f2bf(W[(size_t)k * JD + nn]);
}

// ---- fused SAGE layer: gather-mean -> LDS, dual MFMA, BN+ReLU epilogue -----
// block = 32 nodes, 4 waves. Gather: quarter-wave per node (16 lanes x uint4),
// 2 serial slots/wave, branch-free unroll-8 rounds via zero-row clamping.
template<bool T3>
__global__ __launch_bounds__(256) void k_fused(const unsigned short* __restrict__ feat,
                                               const int* __restrict__ cnt, const int* __restrict__ bucket,
                                               const unsigned short* __restrict__ Bl, const unsigned short* __restrict__ Br,
                                               const float* __restrict__ scale, const float* __restrict__ shift,
                                               unsigned short* __restrict__ out,
                                               const unsigned short* __restrict__ W3p, unsigned short* __restrict__ t3,
                                               int n) {
    __shared__ unsigned short sA[32 * 136];
    __shared__ unsigned short sH[T3 ? 32 * 136 : 8];
    const int tid  = threadIdx.x;
    const int wave = tid >> 6;
    const int lane = tid & 63;
    const int nb0  = blockIdx.x * 32;
    if (nb0 >= n) return;

    // ---- phase 1: gather-mean ----------------------------------------------
    {
        const int q4   = lane >> 4;
        const int li   = lane & 15;
        const int base = q4 << 4;
        const uint4* inp = (const uint4*)feat;     // 256B row = 16 x uint4
        int rows[2], cs[2], idxs[2];
        #pragma unroll
        for (int t = 0; t < 2; t++) {
            rows[t] = wave * 8 + t * 4 + q4;
            int node = nb0 + rows[t];
            bool ok = node < n;
            int c = ok ? cnt[node] : 0; if (c > CAP) c = CAP;
            cs[t] = c;
            idxs[t] = (ok && li < c) ? bucket[(size_t)node * CAP + li] : n;  // n = zero row
        }
        #pragma unroll
        for (int t = 0; t < 2; t++) {
            const int c = cs[t];
            float a[8] = {0.f, 0.f, 0.f, 0.f, 0.f, 0.f, 0.f, 0.f};
            if (c > 0) {
                #pragma unroll
                for (int u = 0; u < 8; u++) {
                    int idx = __shfl(idxs[t], base + u);        // >=c lanes hold n (zero row)
                    uint4 v = inp[(size_t)idx * 16 + li];
                    ACC8(v);
                }
            }
            if (c > 8) {
                #pragma unroll
                for (int u = 8; u < 16; u++) {
                    int idx = __shfl(idxs[t], base + u);
                    uint4 v = inp[(size_t)idx * 16 + li];
                    ACC8(v);
                }
            }
            const int node = nb0 + rows[t];
            for (int s = 16; s < c; s++) {                      // deg>16 (rare)
                int idx = bucket[(size_t)node * CAP + s];
                uint4 v = inp[(size_t)idx * 16 + li];
                ACC8(v);
            }
            if (node < n) {
                float iv = 1.0f / fmaxf((float)c, 1.0f);
                uint4 o;
                o.x = (unsigned)f2bf(a[0] * iv) | ((unsigned)f2bf(a[1] * iv) << 16);
                o.y = (unsigned)f2bf(a[2] * iv) | ((unsigned)f2bf(a[3] * iv) << 16);
                o.z = (unsigned)f2bf(a[4] * iv) | ((unsigned)f2bf(a[5] * iv) << 16);
                o.w = (unsigned)f2bf(a[6] * iv) | ((unsigned)f2bf(a[7] * iv) << 16);
                *(uint4*)(sA + rows[t] * 136 + li * 8) = o;
            }
        }
    }
    __syncthreads();

    // ---- phase 2: dual MFMA, wave = 32 rows x 32 cols (nt0 = wave*2) --------
    const int m = lane & 15;
    const int q = lane >> 4;
    const int nt0 = wave * 2;
    const int rg0 = min(nb0 + m,      n - 1);
    const int rg1 = min(nb0 + 16 + m, n - 1);

    f4v acc[2][2];
    #pragma unroll
    for (int mt = 0; mt < 2; mt++)
        #pragma unroll
        for (int c = 0; c < 2; c++) {
            acc[mt][c][0] = 0.f; acc[mt][c][1] = 0.f; acc[mt][c][2] = 0.f; acc[mt][c][3] = 0.f;
        }

    #pragma unroll
    for (int kt = 0; kt < 4; kt++) {
        const int ko = kt * 32 + q * 8;
        s8v a0 = *(const s8v*)(sA + m * 136 + ko);                // agg side (LDS)
        s8v a1 = *(const s8v*)(sA + (16 + m) * 136 + ko);
        s8v a0d = *(const s8v*)(feat + (size_t)rg0 * 128 + ko);   // root side (global)
        s8v a1d = *(const s8v*)(feat + (size_t)rg1 * 128 + ko);
        #pragma unroll
        for (int c = 0; c < 2; c++) {
            s8v b  = *(const s8v*)(Bl + ((size_t)(kt * 8 + nt0 + c) * 64 + lane) * 8);
            acc[0][c] = __builtin_amdgcn_mfma_f32_16x16x32_bf16(a0, b, acc[0][c], 0, 0, 0);
            acc[1][c] = __builtin_amdgcn_mfma_f32_16x16x32_bf16(a1, b, acc[1][c], 0, 0, 0);
            s8v b2 = *(const s8v*)(Br + ((size_t)(kt * 8 + nt0 + c) * 64 + lane) * 8);
            acc[0][c] = __builtin_amdgcn_mfma_f32_16x16x32_bf16(a0d, b2, acc[0][c], 0, 0, 0);
            acc[1][c] = __builtin_amdgcn_mfma_f32_16x16x32_bf16(a1d, b2, acc[1][c], 0, 0, 0);
        }
    }

    // ---- epilogue: BN+ReLU, write bf16 (and stash tile for t3) -------------
    float scv[2], shv[2];
    #pragma unroll
    for (int c = 0; c < 2; c++) {
        int col = (nt0 + c) * 16 + m;
        scv[c] = scale[col]; shv[c] = shift[col];
    }
    #pragma unroll
    for (int mt = 0; mt < 2; mt++) {
        #pragma unroll
        for (int reg = 0; reg < 4; reg++) {
            int rloc = mt * 16 + q * 4 + reg;
            int row  = nb0 + rloc;
            if (row < n) {
                #pragma unroll
                for (int c = 0; c < 2; c++) {
                    int col = (nt0 + c) * 16 + m;
                    float v = fmaxf(acc[mt][c][reg] * scv[c] + shv[c], 0.f);
                    unsigned short u = f2bf(v);
                    out[(size_t)row * 128 + col] = u;
                    if constexpr (T3) sH[rloc * 136 + col] = u;
                }
            }
        }
    }

    // ---- phase 3 (layer 2 only): t3 = hb2_tile @ Wl3, wave = 16 cols -------
    if constexpr (T3) {
        __syncthreads();
        f4v a3c[2];
        #pragma unroll
        for (int mt = 0; mt < 2; mt++) { a3c[mt][0] = 0.f; a3c[mt][1] = 0.f; a3c[mt][2] = 0.f; a3c[mt][3] = 0.f; }
        #pragma unroll
        for (int kt = 0; kt < 4; kt++) {
            const int ko = kt * 32 + q * 8;
            s8v a0 = *(const s8v*)(sH + m * 136 + ko);
            s8v a1 = *(const s8v*)(sH + (16 + m) * 136 + ko);
            s8v b  = *(const s8v*)(W3p + ((size_t)(kt * 4 + wave) * 64 + lane) * 8);
            a3c[0] = __builtin_amdgcn_mfma_f32_16x16x32_bf16(a0, b, a3c[0], 0, 0, 0);
            a3c[1] = __builtin_amdgcn_mfma_f32_16x16x32_bf16(a1, b, a3c[1], 0, 0, 0);
        }
        #pragma unroll
        for (int mt = 0; mt < 2; mt++) {
            #pragma unroll
            for (int reg = 0; reg < 4; reg++) {
                int row = nb0 + mt * 16 + q * 4 + reg;
                if (row < n) t3[(size_t)row * 64 + wave * 16 + m] = f2bf(a3c[mt][reg]);
            }
        }
    }
}

// ---- fused layer 3: gather-mean(t3) + hb2@Wr3 + bias -----------------------
// block = 32 nodes, 4 waves. Gather: eighth-wave per node (8 lanes x uint4),
// 8 nodes concurrent per wave, 1 slot, branch-free unroll-8 rounds.
__global__ __launch_bounds__(256) void k_final(const unsigned short* __restrict__ hb2,
                                               const unsigned short* __restrict__ t3,
                                               const int* __restrict__ cnt, const int* __restrict__ bucket,
                                               const unsigned short* __restrict__ Bp, const float* __restrict__ bias,
                                               float* __restrict__ outf, int n) {
    __shared__ float sG[32 * 68];   // fp32 agg tile, stride 68 floats
    const int tid  = threadIdx.x;
    const int wave = tid >> 6;
    const int lane = tid & 63;
    const int nb0  = blockIdx.x * 32;
    if (nb0 >= n) return;

    // ---- phase 1: gather-mean ----------------------------------------------
    {
        const int e8   = lane >> 3;
        const int li   = lane & 7;
        const int base = e8 << 3;
        const uint4* inp = (const uint4*)t3;       // 128B row = 8 x uint4
        const int row  = wave * 8 + e8;
        const int node = nb0 + row;
        const bool ok  = node < n;
        int c = ok ? cnt[node] : 0; if (c > CAP) c = CAP;
        int idx1 = (ok && li < c)     ? bucket[(size_t)node * CAP + li]     : n;
        int idx2 = (ok && li + 8 < c) ? bucket[(size_t)node * CAP + li + 8] : n;
        float a[8] = {0.f, 0.f, 0.f, 0.f, 0.f, 0.f, 0.f, 0.f};
        if (c > 0) {
            #pragma unroll
            for (int u = 0; u < 8; u++) {
                int idx = __shfl(idx1, base + u);
                uint4 v = inp[(size_t)idx * 8 + li];
                ACC8(v);
            }
        }
        if (c > 8) {
            #pragma unroll
            for (int u = 0; u < 8; u++) {
                int idx = __shfl(idx2, base + u);
                uint4 v = inp[(size_t)idx * 8 + li];
                ACC8(v);
            }
        }
        for (int s = 16; s < c; s++) {             // deg>16 (rare)
            int idx = bucket[(size_t)node * CAP + s];
            uint4 v = inp[(size_t)idx * 8 + li];
            ACC8(v);
        }
        if (ok) {
            float iv = 1.0f / fmaxf((float)c, 1.0f);
            float4 o1; o1.x = a[0] * iv; o1.y = a[1] * iv; o1.z = a[2] * iv; o1.w = a[3] * iv;
            float4 o2; o2.x = a[4] * iv; o2.y = a[5] * iv; o2.z = a[6] * iv; o2.w = a[7] * iv;
            *(float4*)(sG + row * 68 + li * 8)     = o1;
            *(float4*)(sG + row * 68 + li * 8 + 4) = o2;
        }
    }
    __syncthreads();

    // ---- phase 2: out = hb2 @ Wr3 + agg + bias ------------------------------
    const int m = lane & 15;
    const int q = lane >> 4;
    const int rg0 = min(nb0 + m,      n - 1);
    const int rg1 = min(nb0 + 16 + m, n - 1);

    f4v acc[2];
    #pragma unroll
    for (int mt = 0; mt < 2; mt++) { acc[mt][0] = 0.f; acc[mt][1] = 0.f; acc[mt][2] = 0.f; acc[mt][3] = 0.f; }

    #pragma unroll
    for (int kt = 0; kt < 4; kt++) {
        const int ko = kt * 32 + q * 8;
        s8v a0 = *(const s8v*)(hb2 + (size_t)rg0 * 128 + ko);
        s8v a1 = *(const s8v*)(hb2 + (size_t)rg1 * 128 + ko);
        s8v b  = *(const s8v*)(Bp + ((size_t)(kt * 4 + wave) * 64 + lane) * 8);
        acc[0] = __builtin_amdgcn_mfma_f32_16x16x32_bf16(a0, b, acc[0], 0, 0, 0);
        acc[1] = __builtin_amdgcn_mfma_f32_16x16x32_bf16(a1, b, acc[1], 0, 0, 0);
    }

    const int col = wave * 16 + m;
    const float bv = bias[col];
    #pragma unroll
    for (int mt = 0; mt < 2; mt++) {
        #pragma unroll
        for (int reg = 0; reg < 4; reg++) {
            int rloc = mt * 16 + q * 4 + reg;
            int row  = nb0 + rloc;
            if (row < n) outf[(size_t)row * 64 + col] = acc[mt][reg] + sG[rloc * 68 + col] + bv;
        }
    }
}

extern "C" void kernel_launch(void* const* d_in, const int* in_sizes, int n_in,
                              void* d_out, int out_size, void* d_ws, size_t ws_size,
                              hipStream_t stream) {
    const float* x   = (const float*)d_in[0];
    const int*   ei  = (const int*)d_in[1];
    const float* Wl1 = (const float*)d_in[2];
    const float* bl1 = (const float*)d_in[3];
    const float* Wr1 = (const float*)d_in[4];
    const float* g1  = (const float*)d_in[5];
    const float* be1 = (const float*)d_in[6];
    const float* rm1 = (const float*)d_in[7];
    const float* rv1 = (const float*)d_in[8];
    const float* Wl2 = (const float*)d_in[9];
    const float* bl2 = (const float*)d_in[10];
    const float* Wr2 = (const float*)d_in[11];
    const float* g2  = (const float*)d_in[12];
    const float* be2 = (const float*)d_in[13];
    const float* rm2 = (const float*)d_in[14];
    const float* rv2 = (const float*)d_in[15];
    const float* Wl3 = (const float*)d_in[16];
    const float* bl3 = (const float*)d_in[17];
    const float* Wr3 = (const float*)d_in[18];

    const int N = in_sizes[0] / 128;
    const int E = in_sizes[1] / 2;
    const int* src = ei;
    const int* dst = ei + E;

    // workspace layout (feature buffers have N+1 rows; row N is the zero row)
    char* w = (char*)d_ws;
    auto au = [](size_t v) { return (v + 1023) & ~(size_t)1023; };
    size_t off = 0;
    int*            cnt    = (int*)(w + off);            off += au((size_t)N * 4);
    int*            bucket = (int*)(w + off);            off += au((size_t)N * CAP * 4);
    unsigned short* xb     = (unsigned short*)(w + off); off += au((size_t)(N + 1) * 128 * 2);
    unsigned short* hb     = (unsigned short*)(w + off); off += au((size_t)(N + 1) * 128 * 2);
    unsigned short* hb2    = (unsigned short*)(w + off); off += au((size_t)(N + 1) * 128 * 2);
    unsigned short* t3b    = (unsigned short*)(w + off); off += au((size_t)(N + 1) * 64 * 2);
    unsigned short* Wp[6];
    Wp[0] = (unsigned short*)(w + off); off += au(128 * 128 * 2);  // Wl1
    Wp[1] = (unsigned short*)(w + off); off += au(128 * 128 * 2);  // Wr1
    Wp[2] = (unsigned short*)(w + off); off += au(128 * 128 * 2);  // Wl2
    Wp[3] = (unsigned short*)(w + off); off += au(128 * 128 * 2);  // Wr2
    Wp[4] = (unsigned short*)(w + off); off += au(128 * 64 * 2);   // Wl3
    Wp[5] = (unsigned short*)(w + off); off += au(128 * 64 * 2);   // Wr3
    float* P = (float*)(w + off); off += 2048;
    (void)ws_size; (void)n_in;

    hipMemsetAsync(cnt, 0, (size_t)N * 4, stream);

    const int n4 = N * 32;
    const int nbBucket = (E + 255) / 256;
    const int nbCvt    = (n4 + 255) / 256;
    k_prep<<<nbBucket + nbCvt + 448, 256, 0, stream>>>(src, dst, E, cnt, bucket,
                                                       x, xb, n4,
                                                       Wl1, Wr1, Wl2, Wr2, Wl3, Wr3,
                                                       Wp[0], Wp[1], Wp[2], Wp[3], Wp[4], Wp[5],
                                                       g1, be1, rm1, rv1, bl1, g2, be2, rm2, rv2, bl2, P,
                                                       hb, hb2, t3b, N, nbBucket, nbCvt);

    const int grid = (N + 31) / 32;

    // layer 1: hb = relu(bn(agg(x)@Wl1 + bl1 + x@Wr1))
    k_fused<false><<<grid, 256, 0, stream>>>(xb, cnt, bucket, Wp[0], Wp[1],
                                             P, P + 128, hb, nullptr, nullptr, N);
    // layer 2: hb2 = relu(bn(agg(hb)@Wl2 + bl2 + hb@Wr2)); t3b = hb2@Wl3
    k_fused<true><<<grid, 256, 0, stream>>>(hb, cnt, bucket, Wp[2], Wp[3],
                                            P + 256, P + 384, hb2, Wp[4], t3b, N);
    // layer 3: out = agg(t3b) + hb2@Wr3 + bl3
    k_final<<<grid, 256, 0, stream>>>(hb2, t3b, cnt, bucket, Wp[5], bl3, (float*)d_out, N);
}